// Round 1
// 469.452 us; speedup vs baseline: 1.0176x; 1.0176x over previous
//
#include <hip/hip_runtime.h>

// Problem constants: T=8, B=16, C_in=C_out=256, M=1024
#define TT 8
#define BB 16
#define CC 256
#define MM 1024
#define NY 33554432   // T*B*C*M elements of y

// ---------------------------------------------------------------------------
// Bit-exact numpy-fp32 semantics (verified PASS R5/R6/R8 incl. replay checks):
//  - einsum('oc,tbcm->tbom'): per element, sequential ascending-c chain,
//    fl32(acc + fl32(w*x)) with separate mul/add roundings (no FMA)
//  - mean/var: numpy pairwise_sum per 1024-row + sequential fp32 carry over
//    the 128 (t,b) slabs; /2^17 exact
//  - rs = fl(1/fl(sqrt(fl(var+1e-5)))); BN affine with correctly-rounded ops
//  - LIF: v = fl(v + fl(fl(yn - v)*0.5)); s = (v>=1); hard reset
// R10 changes (graph restructure, all op chains bit-identical):
//  - mean partials fused INTO einsum kernel (rows reduced from the very
//    registers that produced them; K2's 128MB y re-read eliminated).
//    LDS staging rows padded 128->132 elems per sub-block: kills the 8-way
//    read bank conflict of the standalone reducer, values/order unchanged.
//  - reduce_var fused into lif kernel (identical sequential chain per o,
//    duplicated per block; single-block kernel + launch gap eliminated).
// ---------------------------------------------------------------------------

// ---------------------------------------------------------------------------
// K1: einsum, 16 o-rows per block, x prefetched one 4-c group ahead,
// + fused mean partials. Grid 2048 linear, XCD swizzle as R8/R9.
// Per-element c-chain identical to verified R5/R6/R8.
// ---------------------------------------------------------------------------
__global__ __launch_bounds__(256) void einsum_store_mean(
    const float* __restrict__ x, const float* __restrict__ W,
    float* __restrict__ y, float* __restrict__ part)
{
    __shared__ float wt[CC][16];        // [c][o'] : 16 KB
    __shared__ float yrow[4][1056];     // 8 blks * 132 (pad 128->132): 16.5 KB
    __shared__ float scratch[4][64];    // 1 KB
    const int tid = threadIdx.x;
    const int lin = blockIdx.x;          // 0..2047
    const int xcd = lin & 7;
    const int j   = lin >> 3;            // 0..255
    const int og  = j & 15;              // o block: 16 channels
    const int tb  = xcd * 16 + (j >> 4); // 0..127
    const int m0  = tid * 4;

#pragma unroll
    for (int i = 0; i < 16; ++i)
        wt[tid][i] = W[(size_t)(og * 16 + i) * CC + tid];
    __syncthreads();

    const float* xs = x + (size_t)tb * (CC * MM) + m0;

    float a[16][4];
#pragma unroll
    for (int i = 0; i < 16; ++i)
#pragma unroll
        for (int q = 0; q < 4; ++q) a[i][q] = 0.0f;

    float4 xb[4];
#pragma unroll
    for (int q = 0; q < 4; ++q)
        xb[q] = *(const float4*)(xs + (size_t)q * MM);

    for (int cb = 0; cb < CC; cb += 4) {
        float4 xn[4];
        const bool more = (cb + 4 < CC);
        if (more) {
#pragma unroll
            for (int q = 0; q < 4; ++q)
                xn[q] = *(const float4*)(xs + (size_t)(cb + 4 + q) * MM);
        }
#pragma unroll
        for (int q = 0; q < 4; ++q) {
            const int c = cb + q;
            const float4 w0 = *(const float4*)&wt[c][0];    // broadcast reads
            const float4 w1 = *(const float4*)&wt[c][4];
            const float4 w2 = *(const float4*)&wt[c][8];
            const float4 w3 = *(const float4*)&wt[c][12];
            const float wv[16] = {w0.x, w0.y, w0.z, w0.w,
                                  w1.x, w1.y, w1.z, w1.w,
                                  w2.x, w2.y, w2.z, w2.w,
                                  w3.x, w3.y, w3.z, w3.w};
#pragma unroll
            for (int i = 0; i < 16; ++i) {
                a[i][0] = __fadd_rn(a[i][0], __fmul_rn(wv[i], xb[q].x));
                a[i][1] = __fadd_rn(a[i][1], __fmul_rn(wv[i], xb[q].y));
                a[i][2] = __fadd_rn(a[i][2], __fmul_rn(wv[i], xb[q].z));
                a[i][3] = __fadd_rn(a[i][3], __fmul_rn(wv[i], xb[q].w));
            }
        }
        if (more) {
#pragma unroll
            for (int q = 0; q < 4; ++q) xb[q] = xn[q];
        }
    }

#pragma unroll
    for (int i = 0; i < 16; ++i) {
        const int o = og * 16 + i;
        *(float4*)(y + ((size_t)tb * CC + o) * MM + m0) =
            make_float4(a[i][0], a[i][1], a[i][2], a[i][3]);
    }

    // ---- fused mean partials: np pairwise per row, from the same registers.
    // Padded layout: element index blk*132 + (m&127); values and summation
    // order identical to verified np_pairwise_1024 (pad only moves addresses).
    const int g    = tid >> 6;      // wave group 0..3 -> reduces row 4r+g
    const int lane = tid & 63;
    const int blk  = m0 >> 7;       // 0..7
    const int off  = m0 & 127;      // multiple of 4 -> float4 aligned w/ pad 4
#pragma unroll
    for (int r = 0; r < 4; ++r) {
        __syncthreads();   // prev round's readers done before overwrite
#pragma unroll
        for (int g2 = 0; g2 < 4; ++g2) {
            const int i = r * 4 + g2;            // compile-time index into a
            *(float4*)&yrow[g2][blk * 132 + off] =
                make_float4(a[i][0], a[i][1], a[i][2], a[i][3]);
        }
        __syncthreads();
        {
            const int b2 = lane >> 3;            // 0..7
            const int k  = lane & 7;             // 0..7
            const float* p = &yrow[g][b2 * 132 + k];
            float rr = p[0];
#pragma unroll
            for (int i2 = 1; i2 < 16; ++i2) rr = __fadd_rn(rr, p[8 * i2]);
            scratch[g][lane] = rr;
        }
        __syncthreads();
        if (lane == 0) {
            float Bv[8];
#pragma unroll
            for (int b2 = 0; b2 < 8; ++b2) {
                const float* rp = &scratch[g][b2 * 8];
                const float s01 = __fadd_rn(rp[0], rp[1]);
                const float s23 = __fadd_rn(rp[2], rp[3]);
                const float s45 = __fadd_rn(rp[4], rp[5]);
                const float s67 = __fadd_rn(rp[6], rp[7]);
                Bv[b2] = __fadd_rn(__fadd_rn(s01, s23), __fadd_rn(s45, s67));
            }
            const float c0 = __fadd_rn(Bv[0], Bv[1]);
            const float c1 = __fadd_rn(Bv[2], Bv[3]);
            const float c2 = __fadd_rn(Bv[4], Bv[5]);
            const float c3 = __fadd_rn(Bv[6], Bv[7]);
            part[(size_t)tb * 256 + og * 16 + r * 4 + g] =
                __fadd_rn(__fadd_rn(c0, c1), __fadd_rn(c2, c3));
        }
    }
}

__global__ void reduce_mean(const float* __restrict__ part,
                            float* __restrict__ mv)
{
    const int o = threadIdx.x;
    float S = 0.0f;
    for (int tb = 0; tb < 128; ++tb)
        S = __fadd_rn(S, part[(size_t)tb * 256 + o]);
    mv[o] = S * (1.0f / 131072.0f);   // /2^17 exact
}

// ---------------------------------------------------------------------------
// K3: var partials from stored y, 4 rows per block (R8/R9 verbatim).
// ---------------------------------------------------------------------------
__global__ __launch_bounds__(256) void var_partial_y(
    const float* __restrict__ y, const float* __restrict__ mv,
    float* __restrict__ part)
{
    __shared__ float yrow[4][1024];
    __shared__ float scratch[4][64];
    const int tid  = threadIdx.x;
    const int g    = tid >> 6;
    const int lane = tid & 63;
    const size_t row = (size_t)blockIdx.x * 4 + g;
    const float* yr = y + row * MM;
    const float mean = mv[row & 255];

#pragma unroll
    for (int q = 0; q < 4; ++q) {
        const float4 yv = *(const float4*)(yr + q * 256 + lane * 4);
        const float d0 = __fsub_rn(yv.x, mean);
        const float d1 = __fsub_rn(yv.y, mean);
        const float d2 = __fsub_rn(yv.z, mean);
        const float d3 = __fsub_rn(yv.w, mean);
        *(float4*)&yrow[g][q * 256 + lane * 4] =
            make_float4(__fmul_rn(d0, d0), __fmul_rn(d1, d1),
                        __fmul_rn(d2, d2), __fmul_rn(d3, d3));
    }
    __syncthreads();

    {
        const int blk = lane >> 3;
        const int k   = lane & 7;
        const float* p = &yrow[g][blk * 128 + k];
        float r = p[0];
#pragma unroll
        for (int i = 1; i < 16; ++i) r = __fadd_rn(r, p[8 * i]);
        scratch[g][lane] = r;
    }
    __syncthreads();

    if (lane == 0) {
        float B[8];
#pragma unroll
        for (int b2 = 0; b2 < 8; ++b2) {
            const float* r = &scratch[g][b2 * 8];
            const float s01 = __fadd_rn(r[0], r[1]);
            const float s23 = __fadd_rn(r[2], r[3]);
            const float s45 = __fadd_rn(r[4], r[5]);
            const float s67 = __fadd_rn(r[6], r[7]);
            B[b2] = __fadd_rn(__fadd_rn(s01, s23), __fadd_rn(s45, s67));
        }
        const float c0 = __fadd_rn(B[0], B[1]);
        const float c1 = __fadd_rn(B[2], B[3]);
        const float c2 = __fadd_rn(B[4], B[5]);
        const float c3 = __fadd_rn(B[6], B[7]);
        part[row] = __fadd_rn(__fadd_rn(c0, c1), __fadd_rn(c2, c3));
    }
}

// ---------------------------------------------------------------------------
// K4: BN + LIF from stored y, with reduce_var fused (identical op chain:
// sequential ascending-tb fadd, *2^-17, +1e-5, rcp(sqrt)). Uniform per block.
// grid (o=256, b=16), 4 m per thread.
// ---------------------------------------------------------------------------
__global__ __launch_bounds__(256) void lif_from_y(
    const float* __restrict__ y, const float* __restrict__ mv,
    const float* __restrict__ part,
    const float* __restrict__ gamma, const float* __restrict__ beta,
    float* __restrict__ out)
{
    const int tid = threadIdx.x;
    const int o = blockIdx.x;
    const int b = blockIdx.y;
    const int m0 = tid * 4;

    const float mean = mv[o];

    // fused reduce_var: exact chain of the former single-block kernel
    float S = 0.0f;
    for (int tb = 0; tb < 128; ++tb)
        S = __fadd_rn(S, part[(size_t)tb * 256 + o]);
    const float var = S * (1.0f / 131072.0f);
    const float vp  = __fadd_rn(var, 1e-5f);
    const float rs  = __fdiv_rn(1.0f, __fsqrt_rn(vp));

    const float g    = gamma[o];
    const float be   = beta[o];

    float v0 = 0.0f, v1 = 0.0f, v2 = 0.0f, v3 = 0.0f;

    for (int t = 0; t < TT; ++t) {
        const size_t off = ((size_t)(t * BB + b) * CC + o) * MM + m0;
        const float4 yv = *(const float4*)(y + off);

        const float n0 = __fadd_rn(__fmul_rn(__fmul_rn(__fsub_rn(yv.x, mean), rs), g), be);
        const float n1 = __fadd_rn(__fmul_rn(__fmul_rn(__fsub_rn(yv.y, mean), rs), g), be);
        const float n2 = __fadd_rn(__fmul_rn(__fmul_rn(__fsub_rn(yv.z, mean), rs), g), be);
        const float n3 = __fadd_rn(__fmul_rn(__fmul_rn(__fsub_rn(yv.w, mean), rs), g), be);

        v0 = __fadd_rn(v0, __fmul_rn(__fsub_rn(n0, v0), 0.5f));
        v1 = __fadd_rn(v1, __fmul_rn(__fsub_rn(n1, v1), 0.5f));
        v2 = __fadd_rn(v2, __fmul_rn(__fsub_rn(n2, v2), 0.5f));
        v3 = __fadd_rn(v3, __fmul_rn(__fsub_rn(n3, v3), 0.5f));

        const bool s0 = (v0 >= 1.0f);
        const bool s1 = (v1 >= 1.0f);
        const bool s2 = (v2 >= 1.0f);
        const bool s3 = (v3 >= 1.0f);
        if (s0) v0 = 0.0f;
        if (s1) v1 = 0.0f;
        if (s2) v2 = 0.0f;
        if (s3) v3 = 0.0f;

        *(float4*)(out + off) = make_float4(s0 ? 1.0f : 0.0f, s1 ? 1.0f : 0.0f,
                                            s2 ? 1.0f : 0.0f, s3 ? 1.0f : 0.0f);
    }
}

// ---------------------------------------------------------------------------
// reduce_var kept for the fallback path only.
// ---------------------------------------------------------------------------
__global__ void reduce_var(const float* __restrict__ part,
                           float* __restrict__ mv)
{
    const int o = threadIdx.x;
    float S = 0.0f;
    for (int tb = 0; tb < 128; ++tb)
        S = __fadd_rn(S, part[(size_t)tb * 256 + o]);
    const float var = S * (1.0f / 131072.0f);
    const float vp  = __fadd_rn(var, 1e-5f);
    mv[256 + o] = __fdiv_rn(1.0f, __fsqrt_rn(vp));
}

// ---------------------------------------------------------------------------
// Fallback path (R5, verified): recompute einsum in each pass. Only used if
// ws cannot hold y (not expected on this harness).
// ---------------------------------------------------------------------------
__device__ __forceinline__ void e1_row4(
    const float* __restrict__ x, const float* __restrict__ W,
    int t, int b, int o, int m0,
    float& y0, float& y1, float& y2, float& y3)
{
    const float* xs = x + ((size_t)(t * BB + b) * CC) * MM + m0;
    const float* wr = W + (size_t)o * CC;
    y0 = 0.0f; y1 = 0.0f; y2 = 0.0f; y3 = 0.0f;
    for (int c = 0; c < CC; ++c) {
        const float wc = wr[c];
        const float4 xv = *(const float4*)(xs + (size_t)c * MM);
        y0 = __fadd_rn(y0, __fmul_rn(wc, xv.x));
        y1 = __fadd_rn(y1, __fmul_rn(wc, xv.y));
        y2 = __fadd_rn(y2, __fmul_rn(wc, xv.z));
        y3 = __fadd_rn(y3, __fmul_rn(wc, xv.w));
    }
}

__device__ __forceinline__ float np_pairwise_1024(
    const float* __restrict__ yrow, float* __restrict__ scratch, int tid)
{
    if (tid < 64) {
        const int blk = tid >> 3;
        const int k   = tid & 7;
        const float* p = yrow + blk * 128 + k;
        float r = p[0];
#pragma unroll
        for (int i = 1; i < 16; ++i) r = __fadd_rn(r, p[8 * i]);
        scratch[tid] = r;
    }
    __syncthreads();
    if (tid == 0) {
        float B[8];
#pragma unroll
        for (int blk = 0; blk < 8; ++blk) {
            const float* r = scratch + blk * 8;
            const float s01 = __fadd_rn(r[0], r[1]);
            const float s23 = __fadd_rn(r[2], r[3]);
            const float s45 = __fadd_rn(r[4], r[5]);
            const float s67 = __fadd_rn(r[6], r[7]);
            B[blk] = __fadd_rn(__fadd_rn(s01, s23), __fadd_rn(s45, s67));
        }
        const float c0 = __fadd_rn(B[0], B[1]);
        const float c1 = __fadd_rn(B[2], B[3]);
        const float c2 = __fadd_rn(B[4], B[5]);
        const float c3 = __fadd_rn(B[6], B[7]);
        scratch[64] = __fadd_rn(__fadd_rn(c0, c1), __fadd_rn(c2, c3));
    }
    __syncthreads();
    return scratch[64];
}

__global__ __launch_bounds__(256) void pass_mean_fb(
    const float* __restrict__ x, const float* __restrict__ W,
    float* __restrict__ part)
{
    __shared__ float yrow[1024];
    __shared__ float scratch[65];
    const int tid = threadIdx.x;
    const int o  = blockIdx.x;
    const int tb = blockIdx.y;
    const int m0 = tid * 4;
    float y0, y1, y2, y3;
    e1_row4(x, W, tb >> 4, tb & 15, o, m0, y0, y1, y2, y3);
    *(float4*)&yrow[m0] = make_float4(y0, y1, y2, y3);
    __syncthreads();
    const float P = np_pairwise_1024(yrow, scratch, tid);
    if (tid == 0) part[(size_t)tb * 256 + o] = P;
}

__global__ __launch_bounds__(256) void pass_var_fb(
    const float* __restrict__ x, const float* __restrict__ W,
    const float* __restrict__ mv, float* __restrict__ part)
{
    __shared__ float yrow[1024];
    __shared__ float scratch[65];
    const int tid = threadIdx.x;
    const int o  = blockIdx.x;
    const int tb = blockIdx.y;
    const int m0 = tid * 4;
    const float mean = mv[o];
    float y0, y1, y2, y3;
    e1_row4(x, W, tb >> 4, tb & 15, o, m0, y0, y1, y2, y3);
    const float d0 = __fsub_rn(y0, mean);
    const float d1 = __fsub_rn(y1, mean);
    const float d2 = __fsub_rn(y2, mean);
    const float d3 = __fsub_rn(y3, mean);
    *(float4*)&yrow[m0] = make_float4(__fmul_rn(d0, d0), __fmul_rn(d1, d1),
                                      __fmul_rn(d2, d2), __fmul_rn(d3, d3));
    __syncthreads();
    const float P = np_pairwise_1024(yrow, scratch, tid);
    if (tid == 0) part[(size_t)tb * 256 + o] = P;
}

__global__ __launch_bounds__(256) void pass_lif_fb(
    const float* __restrict__ x, const float* __restrict__ W,
    const float* __restrict__ mv,
    const float* __restrict__ gamma, const float* __restrict__ beta,
    float* __restrict__ out)
{
    const int tid = threadIdx.x;
    const int o = blockIdx.x;
    const int b = blockIdx.y;
    const int m0 = tid * 4;
    const float mean = mv[o];
    const float rs   = mv[256 + o];
    const float g    = gamma[o];
    const float be   = beta[o];
    float v0 = 0.0f, v1 = 0.0f, v2 = 0.0f, v3 = 0.0f;
    for (int t = 0; t < TT; ++t) {
        float y0, y1, y2, y3;
        e1_row4(x, W, t, b, o, m0, y0, y1, y2, y3);
        const float n0 = __fadd_rn(__fmul_rn(__fmul_rn(__fsub_rn(y0, mean), rs), g), be);
        const float n1 = __fadd_rn(__fmul_rn(__fmul_rn(__fsub_rn(y1, mean), rs), g), be);
        const float n2 = __fadd_rn(__fmul_rn(__fmul_rn(__fsub_rn(y2, mean), rs), g), be);
        const float n3 = __fadd_rn(__fmul_rn(__fmul_rn(__fsub_rn(y3, mean), rs), g), be);
        v0 = __fadd_rn(v0, __fmul_rn(__fsub_rn(n0, v0), 0.5f));
        v1 = __fadd_rn(v1, __fmul_rn(__fsub_rn(n1, v1), 0.5f));
        v2 = __fadd_rn(v2, __fmul_rn(__fsub_rn(n2, v2), 0.5f));
        v3 = __fadd_rn(v3, __fmul_rn(__fsub_rn(n3, v3), 0.5f));
        const bool s0 = (v0 >= 1.0f);
        const bool s1 = (v1 >= 1.0f);
        const bool s2 = (v2 >= 1.0f);
        const bool s3 = (v3 >= 1.0f);
        if (s0) v0 = 0.0f;
        if (s1) v1 = 0.0f;
        if (s2) v2 = 0.0f;
        if (s3) v3 = 0.0f;
        const size_t off = ((size_t)(t * BB + b) * CC + o) * MM + m0;
        *(float4*)(out + off) = make_float4(s0 ? 1.0f : 0.0f, s1 ? 1.0f : 0.0f,
                                            s2 ? 1.0f : 0.0f, s3 ? 1.0f : 0.0f);
    }
}

// ---------------------------------------------------------------------------
extern "C" void kernel_launch(void* const* d_in, const int* in_sizes, int n_in,
                              void* d_out, int out_size, void* d_ws, size_t ws_size,
                              hipStream_t stream)
{
    const float* x     = (const float*)d_in[0];
    const float* W     = (const float*)d_in[1];
    const float* gamma = (const float*)d_in[2];
    const float* beta  = (const float*)d_in[3];
    float* out = (float*)d_out;

    const size_t need = ((size_t)NY + 128 * 256 + 512) * sizeof(float);

    if (ws_size >= need) {
        float* y    = (float*)d_ws;
        float* part = y + NY;
        float* mv   = part + 128 * 256;

        einsum_store_mean<<<dim3(2048), dim3(256), 0, stream>>>(x, W, y, part);
        reduce_mean<<<dim3(1), dim3(256), 0, stream>>>(part, mv);
        var_partial_y<<<dim3(8192), dim3(256), 0, stream>>>(y, mv, part);
        lif_from_y<<<dim3(256, 16), dim3(256), 0, stream>>>(y, mv, part, gamma, beta, out);
    } else {
        float* part = (float*)d_ws;
        float* mv   = part + 128 * 256;
        pass_mean_fb<<<dim3(256, 128), dim3(256), 0, stream>>>(x, W, part);
        reduce_mean<<<dim3(1), dim3(256), 0, stream>>>(part, mv);
        pass_var_fb<<<dim3(256, 128), dim3(256), 0, stream>>>(x, W, mv, part);
        reduce_var<<<dim3(1), dim3(256), 0, stream>>>(part, mv);
        pass_lif_fb<<<dim3(256, 16), dim3(256), 0, stream>>>(x, W, mv, gamma, beta, out);
    }
}

// Round 3
// 445.918 us; speedup vs baseline: 1.0713x; 1.0528x over previous
//
#include <hip/hip_runtime.h>

// Problem constants: T=8, B=16, C_in=C_out=256, M=1024
#define TT 8
#define BB 16
#define CC 256
#define MM 1024
#define NY 33554432   // T*B*C*M elements of y

typedef float fx4 __attribute__((ext_vector_type(4)));

// ---------------------------------------------------------------------------
// Bit-exact numpy-fp32 semantics (verified PASS R5/R6/R8/R10):
//  - einsum('oc,tbcm->tbom'): per element, sequential ascending-c chain,
//    fl32(acc + fl32(w*x)) with separate mul/add roundings (no FMA)
//  - mean/var: numpy pairwise_sum per 1024-row + sequential fp32 carry over
//    the 128 (t,b) slabs; /2^17 exact
//  - rs = fl(1/fl(sqrt(fl(var+1e-5)))); BN affine with correctly-rounded ops
//  - LIF: v = fl(v + fl(fl(yn - v)*0.5)); s = (v>=1); hard reset
// R12 == R11 resubmitted (previous round failed on container infra, not
// kernel). Changes vs verified R10, all op chains bit-identical:
//  - einsum weights read DIRECTLY from W with block-uniform addressing
//    (scalar s_load path) instead of LDS staging: MAC loop has zero LDS
//    traffic; wt buffer gone (LDS 34.3KB -> 17.9KB)
//  - reduce_mean fused into var_partial (exact ascending-tb chain per wave);
//    main graph is 3 kernels
//  - lif part-chains unrolled (loads pipelined; add order unchanged);
//    out stores nontemporal (y stays L3-resident)
// ---------------------------------------------------------------------------

// ---------------------------------------------------------------------------
// K1: einsum, 16 o-rows per block, x prefetched one 4-c group ahead,
// + fused mean partials. Grid 2048 linear, XCD swizzle as R8-R10.
// Per-element c-chain identical to verified R5/R6/R8/R10.
// ---------------------------------------------------------------------------
__global__ __launch_bounds__(256) void einsum_store_mean(
    const float* __restrict__ x, const float* __restrict__ W,
    float* __restrict__ y, float* __restrict__ part)
{
    __shared__ float yrow[4][1056];     // 8 blks * 132 (pad 128->132): 16.5 KB
    __shared__ float scratch[4][64];    // 1 KB
    const int tid = threadIdx.x;
    const int lin = blockIdx.x;          // 0..2047
    const int xcd = lin & 7;
    const int j   = lin >> 3;            // 0..255
    const int og  = j & 15;              // o block: 16 channels
    const int tb  = xcd * 16 + (j >> 4); // 0..127
    const int m0  = tid * 4;

    const float* __restrict__ Wp = W + (size_t)og * 16 * CC;  // 16 rows
    const float* xs = x + (size_t)tb * (CC * MM) + m0;

    float a[16][4];
#pragma unroll
    for (int i = 0; i < 16; ++i)
#pragma unroll
        for (int q = 0; q < 4; ++q) a[i][q] = 0.0f;

    float4 xb[4];
#pragma unroll
    for (int q = 0; q < 4; ++q)
        xb[q] = *(const float4*)(xs + (size_t)q * MM);

    for (int cb = 0; cb < CC; cb += 4) {
        float4 xn[4];
        const bool more = (cb + 4 < CC);
        if (more) {
#pragma unroll
            for (int q = 0; q < 4; ++q)
                xn[q] = *(const float4*)(xs + (size_t)(cb + 4 + q) * MM);
        }
        // Block-uniform weight loads -> scalar pipe (s_load_dwordx4).
        // wqa[q][i] == W[(og*16+i)*CC + cb + q], same values as R10's wt.
        float wqa[4][16];
#pragma unroll
        for (int i = 0; i < 16; ++i) {
            const float4 wrow = *(const float4*)(Wp + (size_t)i * CC + cb);
            wqa[0][i] = wrow.x; wqa[1][i] = wrow.y;
            wqa[2][i] = wrow.z; wqa[3][i] = wrow.w;
        }
#pragma unroll
        for (int q = 0; q < 4; ++q) {
#pragma unroll
            for (int i = 0; i < 16; ++i) {
                a[i][0] = __fadd_rn(a[i][0], __fmul_rn(wqa[q][i], xb[q].x));
                a[i][1] = __fadd_rn(a[i][1], __fmul_rn(wqa[q][i], xb[q].y));
                a[i][2] = __fadd_rn(a[i][2], __fmul_rn(wqa[q][i], xb[q].z));
                a[i][3] = __fadd_rn(a[i][3], __fmul_rn(wqa[q][i], xb[q].w));
            }
        }
        if (more) {
#pragma unroll
            for (int q = 0; q < 4; ++q) xb[q] = xn[q];
        }
    }

#pragma unroll
    for (int i = 0; i < 16; ++i) {
        const int o = og * 16 + i;
        *(float4*)(y + ((size_t)tb * CC + o) * MM + m0) =
            make_float4(a[i][0], a[i][1], a[i][2], a[i][3]);
    }

    // ---- fused mean partials: np pairwise per row, from the same registers.
    // Padded layout: element index blk*132 + (m&127); values and summation
    // order identical to verified np_pairwise_1024 (pad only moves addresses).
    const int g    = tid >> 6;      // wave group 0..3 -> reduces row 4r+g
    const int lane = tid & 63;
    const int blk  = m0 >> 7;       // 0..7
    const int off  = m0 & 127;      // multiple of 4 -> float4 aligned w/ pad 4
#pragma unroll
    for (int r = 0; r < 4; ++r) {
        __syncthreads();   // prev round's readers done before overwrite
#pragma unroll
        for (int g2 = 0; g2 < 4; ++g2) {
            const int i = r * 4 + g2;            // compile-time index into a
            *(float4*)&yrow[g2][blk * 132 + off] =
                make_float4(a[i][0], a[i][1], a[i][2], a[i][3]);
        }
        __syncthreads();
        {
            const int b2 = lane >> 3;            // 0..7
            const int k  = lane & 7;             // 0..7
            const float* p = &yrow[g][b2 * 132 + k];
            float rr = p[0];
#pragma unroll
            for (int i2 = 1; i2 < 16; ++i2) rr = __fadd_rn(rr, p[8 * i2]);
            scratch[g][lane] = rr;
        }
        __syncthreads();
        if (lane == 0) {
            float Bv[8];
#pragma unroll
            for (int b2 = 0; b2 < 8; ++b2) {
                const float* rp = &scratch[g][b2 * 8];
                const float s01 = __fadd_rn(rp[0], rp[1]);
                const float s23 = __fadd_rn(rp[2], rp[3]);
                const float s45 = __fadd_rn(rp[4], rp[5]);
                const float s67 = __fadd_rn(rp[6], rp[7]);
                Bv[b2] = __fadd_rn(__fadd_rn(s01, s23), __fadd_rn(s45, s67));
            }
            const float c0 = __fadd_rn(Bv[0], Bv[1]);
            const float c1 = __fadd_rn(Bv[2], Bv[3]);
            const float c2 = __fadd_rn(Bv[4], Bv[5]);
            const float c3 = __fadd_rn(Bv[6], Bv[7]);
            part[(size_t)tb * 256 + og * 16 + r * 4 + g] =
                __fadd_rn(__fadd_rn(c0, c1), __fadd_rn(c2, c3));
        }
    }
}

// ---------------------------------------------------------------------------
// K2 (main): var partials from stored y, 4 rows per block, mean computed
// inline per wave (exact reduce_mean chain: ascending tb, then /2^17).
// LDS rows padded 128->132 to kill the 8-way read bank conflict.
// ---------------------------------------------------------------------------
__global__ __launch_bounds__(256) void var_partial_im(
    const float* __restrict__ y, const float* __restrict__ partM,
    float* __restrict__ partV)
{
    __shared__ float yrow[4][1056];
    __shared__ float scratch[4][64];
    const int tid  = threadIdx.x;
    const int g    = tid >> 6;
    const int lane = tid & 63;
    const size_t row = (size_t)blockIdx.x * 4 + g;
    const int o = (int)(row & 255);
    const float* yr = y + row * MM;

    // inline mean: identical chain to reduce_mean
    float S = 0.0f;
#pragma unroll 16
    for (int tb2 = 0; tb2 < 128; ++tb2)
        S = __fadd_rn(S, partM[(size_t)tb2 * 256 + o]);
    const float mean = S * (1.0f / 131072.0f);

#pragma unroll
    for (int q = 0; q < 4; ++q) {
        const int idx = q * 256 + lane * 4;
        const int blk = idx >> 7;
        const int off = idx & 127;
        const float4 yv = *(const float4*)(yr + idx);
        const float d0 = __fsub_rn(yv.x, mean);
        const float d1 = __fsub_rn(yv.y, mean);
        const float d2 = __fsub_rn(yv.z, mean);
        const float d3 = __fsub_rn(yv.w, mean);
        *(float4*)&yrow[g][blk * 132 + off] =
            make_float4(__fmul_rn(d0, d0), __fmul_rn(d1, d1),
                        __fmul_rn(d2, d2), __fmul_rn(d3, d3));
    }
    __syncthreads();

    {
        const int b2 = lane >> 3;
        const int k  = lane & 7;
        const float* p = &yrow[g][b2 * 132 + k];
        float r = p[0];
#pragma unroll
        for (int i = 1; i < 16; ++i) r = __fadd_rn(r, p[8 * i]);
        scratch[g][lane] = r;
    }
    __syncthreads();

    if (lane == 0) {
        float B[8];
#pragma unroll
        for (int b2 = 0; b2 < 8; ++b2) {
            const float* r = &scratch[g][b2 * 8];
            const float s01 = __fadd_rn(r[0], r[1]);
            const float s23 = __fadd_rn(r[2], r[3]);
            const float s45 = __fadd_rn(r[4], r[5]);
            const float s67 = __fadd_rn(r[6], r[7]);
            B[b2] = __fadd_rn(__fadd_rn(s01, s23), __fadd_rn(s45, s67));
        }
        const float c0 = __fadd_rn(B[0], B[1]);
        const float c1 = __fadd_rn(B[2], B[3]);
        const float c2 = __fadd_rn(B[4], B[5]);
        const float c3 = __fadd_rn(B[6], B[7]);
        partV[row] = __fadd_rn(__fadd_rn(c0, c1), __fadd_rn(c2, c3));
    }
}

// ---------------------------------------------------------------------------
// K3 (main): BN + LIF from stored y; mean and rs computed inline from
// partM/partV (exact chains of reduce_mean/reduce_var; block-uniform o
// -> scalar loads, unrolled so latency pipelines). Nontemporal out stores.
// ---------------------------------------------------------------------------
__global__ __launch_bounds__(256) void lif_from_y_im(
    const float* __restrict__ y, const float* __restrict__ partM,
    const float* __restrict__ partV,
    const float* __restrict__ gamma, const float* __restrict__ beta,
    float* __restrict__ out)
{
    const int tid = threadIdx.x;
    const int o = blockIdx.x;
    const int b = blockIdx.y;
    const int m0 = tid * 4;

    float Sm = 0.0f;
#pragma unroll 16
    for (int tb = 0; tb < 128; ++tb)
        Sm = __fadd_rn(Sm, partM[(size_t)tb * 256 + o]);
    const float mean = Sm * (1.0f / 131072.0f);

    float Sv = 0.0f;
#pragma unroll 16
    for (int tb = 0; tb < 128; ++tb)
        Sv = __fadd_rn(Sv, partV[(size_t)tb * 256 + o]);
    const float var = Sv * (1.0f / 131072.0f);
    const float vp  = __fadd_rn(var, 1e-5f);
    const float rs  = __fdiv_rn(1.0f, __fsqrt_rn(vp));

    const float g    = gamma[o];
    const float be   = beta[o];

    float v0 = 0.0f, v1 = 0.0f, v2 = 0.0f, v3 = 0.0f;

    for (int t = 0; t < TT; ++t) {
        const size_t off = ((size_t)(t * BB + b) * CC + o) * MM + m0;
        const float4 yv = *(const float4*)(y + off);

        const float n0 = __fadd_rn(__fmul_rn(__fmul_rn(__fsub_rn(yv.x, mean), rs), g), be);
        const float n1 = __fadd_rn(__fmul_rn(__fmul_rn(__fsub_rn(yv.y, mean), rs), g), be);
        const float n2 = __fadd_rn(__fmul_rn(__fmul_rn(__fsub_rn(yv.z, mean), rs), g), be);
        const float n3 = __fadd_rn(__fmul_rn(__fmul_rn(__fsub_rn(yv.w, mean), rs), g), be);

        v0 = __fadd_rn(v0, __fmul_rn(__fsub_rn(n0, v0), 0.5f));
        v1 = __fadd_rn(v1, __fmul_rn(__fsub_rn(n1, v1), 0.5f));
        v2 = __fadd_rn(v2, __fmul_rn(__fsub_rn(n2, v2), 0.5f));
        v3 = __fadd_rn(v3, __fmul_rn(__fsub_rn(n3, v3), 0.5f));

        const bool s0 = (v0 >= 1.0f);
        const bool s1 = (v1 >= 1.0f);
        const bool s2 = (v2 >= 1.0f);
        const bool s3 = (v3 >= 1.0f);
        if (s0) v0 = 0.0f;
        if (s1) v1 = 0.0f;
        if (s2) v2 = 0.0f;
        if (s3) v3 = 0.0f;

        fx4 sv;
        sv.x = s0 ? 1.0f : 0.0f; sv.y = s1 ? 1.0f : 0.0f;
        sv.z = s2 ? 1.0f : 0.0f; sv.w = s3 ? 1.0f : 0.0f;
        __builtin_nontemporal_store(sv, (fx4*)(out + off));
    }
}

// ---------------------------------------------------------------------------
// Mid path (R10 graph) kernels, kept for the unlikely case ws fits old need
// but not new need.
// ---------------------------------------------------------------------------
__global__ void reduce_mean(const float* __restrict__ part,
                            float* __restrict__ mv)
{
    const int o = threadIdx.x;
    float S = 0.0f;
    for (int tb = 0; tb < 128; ++tb)
        S = __fadd_rn(S, part[(size_t)tb * 256 + o]);
    mv[o] = S * (1.0f / 131072.0f);   // /2^17 exact
}

__global__ __launch_bounds__(256) void var_partial_y(
    const float* __restrict__ y, const float* __restrict__ mv,
    float* __restrict__ part)
{
    __shared__ float yrow[4][1024];
    __shared__ float scratch[4][64];
    const int tid  = threadIdx.x;
    const int g    = tid >> 6;
    const int lane = tid & 63;
    const size_t row = (size_t)blockIdx.x * 4 + g;
    const float* yr = y + row * MM;
    const float mean = mv[row & 255];

#pragma unroll
    for (int q = 0; q < 4; ++q) {
        const float4 yv = *(const float4*)(yr + q * 256 + lane * 4);
        const float d0 = __fsub_rn(yv.x, mean);
        const float d1 = __fsub_rn(yv.y, mean);
        const float d2 = __fsub_rn(yv.z, mean);
        const float d3 = __fsub_rn(yv.w, mean);
        *(float4*)&yrow[g][q * 256 + lane * 4] =
            make_float4(__fmul_rn(d0, d0), __fmul_rn(d1, d1),
                        __fmul_rn(d2, d2), __fmul_rn(d3, d3));
    }
    __syncthreads();

    {
        const int blk = lane >> 3;
        const int k   = lane & 7;
        const float* p = &yrow[g][blk * 128 + k];
        float r = p[0];
#pragma unroll
        for (int i = 1; i < 16; ++i) r = __fadd_rn(r, p[8 * i]);
        scratch[g][lane] = r;
    }
    __syncthreads();

    if (lane == 0) {
        float B[8];
#pragma unroll
        for (int b2 = 0; b2 < 8; ++b2) {
            const float* r = &scratch[g][b2 * 8];
            const float s01 = __fadd_rn(r[0], r[1]);
            const float s23 = __fadd_rn(r[2], r[3]);
            const float s45 = __fadd_rn(r[4], r[5]);
            const float s67 = __fadd_rn(r[6], r[7]);
            B[b2] = __fadd_rn(__fadd_rn(s01, s23), __fadd_rn(s45, s67));
        }
        const float c0 = __fadd_rn(B[0], B[1]);
        const float c1 = __fadd_rn(B[2], B[3]);
        const float c2 = __fadd_rn(B[4], B[5]);
        const float c3 = __fadd_rn(B[6], B[7]);
        part[row] = __fadd_rn(__fadd_rn(c0, c1), __fadd_rn(c2, c3));
    }
}

__global__ __launch_bounds__(256) void lif_from_y(
    const float* __restrict__ y, const float* __restrict__ mv,
    const float* __restrict__ part,
    const float* __restrict__ gamma, const float* __restrict__ beta,
    float* __restrict__ out)
{
    const int tid = threadIdx.x;
    const int o = blockIdx.x;
    const int b = blockIdx.y;
    const int m0 = tid * 4;

    const float mean = mv[o];

    float S = 0.0f;
#pragma unroll 16
    for (int tb = 0; tb < 128; ++tb)
        S = __fadd_rn(S, part[(size_t)tb * 256 + o]);
    const float var = S * (1.0f / 131072.0f);
    const float vp  = __fadd_rn(var, 1e-5f);
    const float rs  = __fdiv_rn(1.0f, __fsqrt_rn(vp));

    const float g    = gamma[o];
    const float be   = beta[o];

    float v0 = 0.0f, v1 = 0.0f, v2 = 0.0f, v3 = 0.0f;

    for (int t = 0; t < TT; ++t) {
        const size_t off = ((size_t)(t * BB + b) * CC + o) * MM + m0;
        const float4 yv = *(const float4*)(y + off);

        const float n0 = __fadd_rn(__fmul_rn(__fmul_rn(__fsub_rn(yv.x, mean), rs), g), be);
        const float n1 = __fadd_rn(__fmul_rn(__fmul_rn(__fsub_rn(yv.y, mean), rs), g), be);
        const float n2 = __fadd_rn(__fmul_rn(__fmul_rn(__fsub_rn(yv.z, mean), rs), g), be);
        const float n3 = __fadd_rn(__fmul_rn(__fmul_rn(__fsub_rn(yv.w, mean), rs), g), be);

        v0 = __fadd_rn(v0, __fmul_rn(__fsub_rn(n0, v0), 0.5f));
        v1 = __fadd_rn(v1, __fmul_rn(__fsub_rn(n1, v1), 0.5f));
        v2 = __fadd_rn(v2, __fmul_rn(__fsub_rn(n2, v2), 0.5f));
        v3 = __fadd_rn(v3, __fmul_rn(__fsub_rn(n3, v3), 0.5f));

        const bool s0 = (v0 >= 1.0f);
        const bool s1 = (v1 >= 1.0f);
        const bool s2 = (v2 >= 1.0f);
        const bool s3 = (v3 >= 1.0f);
        if (s0) v0 = 0.0f;
        if (s1) v1 = 0.0f;
        if (s2) v2 = 0.0f;
        if (s3) v3 = 0.0f;

        *(float4*)(out + off) = make_float4(s0 ? 1.0f : 0.0f, s1 ? 1.0f : 0.0f,
                                            s2 ? 1.0f : 0.0f, s3 ? 1.0f : 0.0f);
    }
}

__global__ void reduce_var(const float* __restrict__ part,
                           float* __restrict__ mv)
{
    const int o = threadIdx.x;
    float S = 0.0f;
    for (int tb = 0; tb < 128; ++tb)
        S = __fadd_rn(S, part[(size_t)tb * 256 + o]);
    const float var = S * (1.0f / 131072.0f);
    const float vp  = __fadd_rn(var, 1e-5f);
    mv[256 + o] = __fdiv_rn(1.0f, __fsqrt_rn(vp));
}

// ---------------------------------------------------------------------------
// Fallback path (R5, verified): recompute einsum in each pass. Only used if
// ws cannot hold y (not expected on this harness).
// ---------------------------------------------------------------------------
__device__ __forceinline__ void e1_row4(
    const float* __restrict__ x, const float* __restrict__ W,
    int t, int b, int o, int m0,
    float& y0, float& y1, float& y2, float& y3)
{
    const float* xs = x + ((size_t)(t * BB + b) * CC) * MM + m0;
    const float* wr = W + (size_t)o * CC;
    y0 = 0.0f; y1 = 0.0f; y2 = 0.0f; y3 = 0.0f;
    for (int c = 0; c < CC; ++c) {
        const float wc = wr[c];
        const float4 xv = *(const float4*)(xs + (size_t)c * MM);
        y0 = __fadd_rn(y0, __fmul_rn(wc, xv.x));
        y1 = __fadd_rn(y1, __fmul_rn(wc, xv.y));
        y2 = __fadd_rn(y2, __fmul_rn(wc, xv.z));
        y3 = __fadd_rn(y3, __fmul_rn(wc, xv.w));
    }
}

__device__ __forceinline__ float np_pairwise_1024(
    const float* __restrict__ yrow, float* __restrict__ scratch, int tid)
{
    if (tid < 64) {
        const int blk = tid >> 3;
        const int k   = tid & 7;
        const float* p = yrow + blk * 128 + k;
        float r = p[0];
#pragma unroll
        for (int i = 1; i < 16; ++i) r = __fadd_rn(r, p[8 * i]);
        scratch[tid] = r;
    }
    __syncthreads();
    if (tid == 0) {
        float B[8];
#pragma unroll
        for (int blk = 0; blk < 8; ++blk) {
            const float* r = scratch + blk * 8;
            const float s01 = __fadd_rn(r[0], r[1]);
            const float s23 = __fadd_rn(r[2], r[3]);
            const float s45 = __fadd_rn(r[4], r[5]);
            const float s67 = __fadd_rn(r[6], r[7]);
            B[blk] = __fadd_rn(__fadd_rn(s01, s23), __fadd_rn(s45, s67));
        }
        const float c0 = __fadd_rn(B[0], B[1]);
        const float c1 = __fadd_rn(B[2], B[3]);
        const float c2 = __fadd_rn(B[4], B[5]);
        const float c3 = __fadd_rn(B[6], B[7]);
        scratch[64] = __fadd_rn(__fadd_rn(c0, c1), __fadd_rn(c2, c3));
    }
    __syncthreads();
    return scratch[64];
}

__global__ __launch_bounds__(256) void pass_mean_fb(
    const float* __restrict__ x, const float* __restrict__ W,
    float* __restrict__ part)
{
    __shared__ float yrow[1024];
    __shared__ float scratch[65];
    const int tid = threadIdx.x;
    const int o  = blockIdx.x;
    const int tb = blockIdx.y;
    const int m0 = tid * 4;
    float y0, y1, y2, y3;
    e1_row4(x, W, tb >> 4, tb & 15, o, m0, y0, y1, y2, y3);
    *(float4*)&yrow[m0] = make_float4(y0, y1, y2, y3);
    __syncthreads();
    const float P = np_pairwise_1024(yrow, scratch, tid);
    if (tid == 0) part[(size_t)tb * 256 + o] = P;
}

__global__ __launch_bounds__(256) void pass_var_fb(
    const float* __restrict__ x, const float* __restrict__ W,
    const float* __restrict__ mv, float* __restrict__ part)
{
    __shared__ float yrow[1024];
    __shared__ float scratch[65];
    const int tid = threadIdx.x;
    const int o  = blockIdx.x;
    const int tb = blockIdx.y;
    const int m0 = tid * 4;
    const float mean = mv[o];
    float y0, y1, y2, y3;
    e1_row4(x, W, tb >> 4, tb & 15, o, m0, y0, y1, y2, y3);
    const float d0 = __fsub_rn(y0, mean);
    const float d1 = __fsub_rn(y1, mean);
    const float d2 = __fsub_rn(y2, mean);
    const float d3 = __fsub_rn(y3, mean);
    *(float4*)&yrow[m0] = make_float4(__fmul_rn(d0, d0), __fmul_rn(d1, d1),
                                      __fmul_rn(d2, d2), __fmul_rn(d3, d3));
    __syncthreads();
    const float P = np_pairwise_1024(yrow, scratch, tid);
    if (tid == 0) part[(size_t)tb * 256 + o] = P;
}

__global__ __launch_bounds__(256) void pass_lif_fb(
    const float* __restrict__ x, const float* __restrict__ W,
    const float* __restrict__ mv,
    const float* __restrict__ gamma, const float* __restrict__ beta,
    float* __restrict__ out)
{
    const int tid = threadIdx.x;
    const int o = blockIdx.x;
    const int b = blockIdx.y;
    const int m0 = tid * 4;
    const float mean = mv[o];
    const float rs   = mv[256 + o];
    const float g    = gamma[o];
    const float be   = beta[o];
    float v0 = 0.0f, v1 = 0.0f, v2 = 0.0f, v3 = 0.0f;
    for (int t = 0; t < TT; ++t) {
        float y0, y1, y2, y3;
        e1_row4(x, W, t, b, o, m0, y0, y1, y2, y3);
        const float n0 = __fadd_rn(__fmul_rn(__fmul_rn(__fsub_rn(y0, mean), rs), g), be);
        const float n1 = __fadd_rn(__fmul_rn(__fmul_rn(__fsub_rn(y1, mean), rs), g), be);
        const float n2 = __fadd_rn(__fmul_rn(__fmul_rn(__fsub_rn(y2, mean), rs), g), be);
        const float n3 = __fadd_rn(__fmul_rn(__fmul_rn(__fsub_rn(y3, mean), rs), g), be);
        v0 = __fadd_rn(v0, __fmul_rn(__fsub_rn(n0, v0), 0.5f));
        v1 = __fadd_rn(v1, __fmul_rn(__fsub_rn(n1, v1), 0.5f));
        v2 = __fadd_rn(v2, __fmul_rn(__fsub_rn(n2, v2), 0.5f));
        v3 = __fadd_rn(v3, __fmul_rn(__fsub_rn(n3, v3), 0.5f));
        const bool s0 = (v0 >= 1.0f);
        const bool s1 = (v1 >= 1.0f);
        const bool s2 = (v2 >= 1.0f);
        const bool s3 = (v3 >= 1.0f);
        if (s0) v0 = 0.0f;
        if (s1) v1 = 0.0f;
        if (s2) v2 = 0.0f;
        if (s3) v3 = 0.0f;
        const size_t off = ((size_t)(t * BB + b) * CC + o) * MM + m0;
        *(float4*)(out + off) = make_float4(s0 ? 1.0f : 0.0f, s1 ? 1.0f : 0.0f,
                                            s2 ? 1.0f : 0.0f, s3 ? 1.0f : 0.0f);
    }
}

// ---------------------------------------------------------------------------
extern "C" void kernel_launch(void* const* d_in, const int* in_sizes, int n_in,
                              void* d_out, int out_size, void* d_ws, size_t ws_size,
                              hipStream_t stream)
{
    const float* x     = (const float*)d_in[0];
    const float* W     = (const float*)d_in[1];
    const float* gamma = (const float*)d_in[2];
    const float* beta  = (const float*)d_in[3];
    float* out = (float*)d_out;

    const size_t need_new = ((size_t)NY + 2 * 128 * 256) * sizeof(float);
    const size_t need_old = ((size_t)NY + 128 * 256 + 512) * sizeof(float);

    if (ws_size >= need_new) {
        float* y     = (float*)d_ws;
        float* partM = y + NY;
        float* partV = partM + 128 * 256;

        einsum_store_mean<<<dim3(2048), dim3(256), 0, stream>>>(x, W, y, partM);
        var_partial_im<<<dim3(8192), dim3(256), 0, stream>>>(y, partM, partV);
        lif_from_y_im<<<dim3(256, 16), dim3(256), 0, stream>>>(y, partM, partV,
                                                               gamma, beta, out);
    } else if (ws_size >= need_old) {
        float* y    = (float*)d_ws;
        float* part = y + NY;
        float* mv   = part + 128 * 256;

        einsum_store_mean<<<dim3(2048), dim3(256), 0, stream>>>(x, W, y, part);
        reduce_mean<<<dim3(1), dim3(256), 0, stream>>>(part, mv);
        var_partial_y<<<dim3(8192), dim3(256), 0, stream>>>(y, mv, part);
        lif_from_y<<<dim3(256, 16), dim3(256), 0, stream>>>(y, mv, part, gamma, beta, out);
    } else {
        float* part = (float*)d_ws;
        float* mv   = part + 128 * 256;
        pass_mean_fb<<<dim3(256, 128), dim3(256), 0, stream>>>(x, W, part);
        reduce_mean<<<dim3(1), dim3(256), 0, stream>>>(part, mv);
        pass_var_fb<<<dim3(256, 128), dim3(256), 0, stream>>>(x, W, mv, part);
        reduce_var<<<dim3(1), dim3(256), 0, stream>>>(part, mv);
        pass_lif_fb<<<dim3(256, 16), dim3(256), 0, stream>>>(x, W, mv, gamma, beta, out);
    }
}

// Round 4
// 428.393 us; speedup vs baseline: 1.1152x; 1.0409x over previous
//
#include <hip/hip_runtime.h>

// Problem constants: T=8, B=16, C_in=C_out=256, M=1024
#define TT 8
#define BB 16
#define CC 256
#define MM 1024
#define NY 33554432   // T*B*C*M elements of y

typedef float fx4 __attribute__((ext_vector_type(4)));

// ---------------------------------------------------------------------------
// Bit-exact numpy-fp32 semantics (verified PASS R5/R6/R8/R10/R12):
//  - einsum('oc,tbcm->tbom'): per element, sequential ascending-c chain,
//    fl32(acc + fl32(w*x)) with separate mul/add roundings (no FMA)
//  - mean/var: numpy pairwise_sum per 1024-row + sequential fp32 carry over
//    the 128 (t,b) slabs; /2^17 exact
//  - rs = fl(1/fl(sqrt(fl(var+1e-5)))); BN affine with correctly-rounded ops
//  - LIF: v = fl(v + fl(fl(yn - v)*0.5)); s = (v>=1); hard reset
// R13 changes vs verified R12 (bit-identical op chains):
//  - einsum K-loop ping-pong unrolled by 8 c's: removes the 16 v_mov buffer
//    copies + the `more` branch per group (~3-4% of issue slots). MAC order
//    still strictly ascending c.
//  - lif mean/rs chains computed by wave 0 only, broadcast via LDS (chains
//    are block-uniform; same adds, same values).
// ---------------------------------------------------------------------------

__device__ __forceinline__ void load4(float4 xb[4],
                                      const float* __restrict__ xs, int cbase)
{
#pragma unroll
    for (int q = 0; q < 4; ++q)
        xb[q] = *(const float4*)(xs + (size_t)(cbase + q) * MM);
}

// One 4-c group of MACs. Weight reads are block-uniform -> scalar pipe.
// wqa[q][i] == W[(og*16+i)*CC + cbase + q]; chain order q(asc) x i, same as
// all verified rounds.
__device__ __forceinline__ void mac_group(float a[16][4], const float4 xb[4],
                                          const float* __restrict__ Wp,
                                          int cbase)
{
    float wqa[4][16];
#pragma unroll
    for (int i = 0; i < 16; ++i) {
        const float4 wrow = *(const float4*)(Wp + (size_t)i * CC + cbase);
        wqa[0][i] = wrow.x; wqa[1][i] = wrow.y;
        wqa[2][i] = wrow.z; wqa[3][i] = wrow.w;
    }
#pragma unroll
    for (int q = 0; q < 4; ++q) {
#pragma unroll
        for (int i = 0; i < 16; ++i) {
            a[i][0] = __fadd_rn(a[i][0], __fmul_rn(wqa[q][i], xb[q].x));
            a[i][1] = __fadd_rn(a[i][1], __fmul_rn(wqa[q][i], xb[q].y));
            a[i][2] = __fadd_rn(a[i][2], __fmul_rn(wqa[q][i], xb[q].z));
            a[i][3] = __fadd_rn(a[i][3], __fmul_rn(wqa[q][i], xb[q].w));
        }
    }
}

// ---------------------------------------------------------------------------
// K1: einsum, 16 o-rows per block, ping-pong x prefetch (8 c's per iter,
// last iter peeled), + fused mean partials. Grid 2048 linear, XCD swizzle.
// Per-element c-chain identical to verified R5-R12.
// ---------------------------------------------------------------------------
__global__ __launch_bounds__(256) void einsum_store_mean(
    const float* __restrict__ x, const float* __restrict__ W,
    float* __restrict__ y, float* __restrict__ part)
{
    __shared__ float yrow[4][1056];     // 8 blks * 132 (pad 128->132): 16.5 KB
    __shared__ float scratch[4][64];    // 1 KB
    const int tid = threadIdx.x;
    const int lin = blockIdx.x;          // 0..2047
    const int xcd = lin & 7;
    const int j   = lin >> 3;            // 0..255
    const int og  = j & 15;              // o block: 16 channels
    const int tb  = xcd * 16 + (j >> 4); // 0..127
    const int m0  = tid * 4;

    const float* __restrict__ Wp = W + (size_t)og * 16 * CC;  // 16 rows
    const float* xs = x + (size_t)tb * (CC * MM) + m0;

    float a[16][4];
#pragma unroll
    for (int i = 0; i < 16; ++i)
#pragma unroll
        for (int q = 0; q < 4; ++q) a[i][q] = 0.0f;

    float4 xA[4], xB[4];
    load4(xA, xs, 0);
    for (int cb = 0; cb < 248; cb += 8) {      // 31 iters: c 0..247
        load4(xB, xs, cb + 4);
        mac_group(a, xA, Wp, cb);
        load4(xA, xs, cb + 8);
        mac_group(a, xB, Wp, cb + 4);
    }
    load4(xB, xs, 252);                         // tail: c 248..255
    mac_group(a, xA, Wp, 248);
    mac_group(a, xB, Wp, 252);

#pragma unroll
    for (int i = 0; i < 16; ++i) {
        const int o = og * 16 + i;
        *(float4*)(y + ((size_t)tb * CC + o) * MM + m0) =
            make_float4(a[i][0], a[i][1], a[i][2], a[i][3]);
    }

    // ---- fused mean partials: np pairwise per row, from the same registers.
    // Padded layout: element index blk*132 + (m&127); values and summation
    // order identical to verified np_pairwise_1024 (pad only moves addresses).
    const int g    = tid >> 6;      // wave group 0..3 -> reduces row 4r+g
    const int lane = tid & 63;
    const int blk  = m0 >> 7;       // 0..7
    const int off  = m0 & 127;      // multiple of 4 -> float4 aligned w/ pad 4
#pragma unroll
    for (int r = 0; r < 4; ++r) {
        __syncthreads();   // prev round's readers done before overwrite
#pragma unroll
        for (int g2 = 0; g2 < 4; ++g2) {
            const int i = r * 4 + g2;            // compile-time index into a
            *(float4*)&yrow[g2][blk * 132 + off] =
                make_float4(a[i][0], a[i][1], a[i][2], a[i][3]);
        }
        __syncthreads();
        {
            const int b2 = lane >> 3;            // 0..7
            const int k  = lane & 7;             // 0..7
            const float* p = &yrow[g][b2 * 132 + k];
            float rr = p[0];
#pragma unroll
            for (int i2 = 1; i2 < 16; ++i2) rr = __fadd_rn(rr, p[8 * i2]);
            scratch[g][lane] = rr;
        }
        __syncthreads();
        if (lane == 0) {
            float Bv[8];
#pragma unroll
            for (int b2 = 0; b2 < 8; ++b2) {
                const float* rp = &scratch[g][b2 * 8];
                const float s01 = __fadd_rn(rp[0], rp[1]);
                const float s23 = __fadd_rn(rp[2], rp[3]);
                const float s45 = __fadd_rn(rp[4], rp[5]);
                const float s67 = __fadd_rn(rp[6], rp[7]);
                Bv[b2] = __fadd_rn(__fadd_rn(s01, s23), __fadd_rn(s45, s67));
            }
            const float c0 = __fadd_rn(Bv[0], Bv[1]);
            const float c1 = __fadd_rn(Bv[2], Bv[3]);
            const float c2 = __fadd_rn(Bv[4], Bv[5]);
            const float c3 = __fadd_rn(Bv[6], Bv[7]);
            part[(size_t)tb * 256 + og * 16 + r * 4 + g] =
                __fadd_rn(__fadd_rn(c0, c1), __fadd_rn(c2, c3));
        }
    }
}

// ---------------------------------------------------------------------------
// K2 (main): var partials from stored y, 4 rows per block, mean computed
// inline per wave (exact reduce_mean chain; per-wave o differs so no
// redundancy). LDS rows padded 128->132 (no 8-way read bank conflict).
// ---------------------------------------------------------------------------
__global__ __launch_bounds__(256) void var_partial_im(
    const float* __restrict__ y, const float* __restrict__ partM,
    float* __restrict__ partV)
{
    __shared__ float yrow[4][1056];
    __shared__ float scratch[4][64];
    const int tid  = threadIdx.x;
    const int g    = tid >> 6;
    const int lane = tid & 63;
    const size_t row = (size_t)blockIdx.x * 4 + g;
    const int o = (int)(row & 255);
    const float* yr = y + row * MM;

    // inline mean: identical chain to reduce_mean
    float S = 0.0f;
#pragma unroll 16
    for (int tb2 = 0; tb2 < 128; ++tb2)
        S = __fadd_rn(S, partM[(size_t)tb2 * 256 + o]);
    const float mean = S * (1.0f / 131072.0f);

#pragma unroll
    for (int q = 0; q < 4; ++q) {
        const int idx = q * 256 + lane * 4;
        const int blk = idx >> 7;
        const int off = idx & 127;
        const float4 yv = *(const float4*)(yr + idx);
        const float d0 = __fsub_rn(yv.x, mean);
        const float d1 = __fsub_rn(yv.y, mean);
        const float d2 = __fsub_rn(yv.z, mean);
        const float d3 = __fsub_rn(yv.w, mean);
        *(float4*)&yrow[g][blk * 132 + off] =
            make_float4(__fmul_rn(d0, d0), __fmul_rn(d1, d1),
                        __fmul_rn(d2, d2), __fmul_rn(d3, d3));
    }
    __syncthreads();

    {
        const int b2 = lane >> 3;
        const int k  = lane & 7;
        const float* p = &yrow[g][b2 * 132 + k];
        float r = p[0];
#pragma unroll
        for (int i = 1; i < 16; ++i) r = __fadd_rn(r, p[8 * i]);
        scratch[g][lane] = r;
    }
    __syncthreads();

    if (lane == 0) {
        float B[8];
#pragma unroll
        for (int b2 = 0; b2 < 8; ++b2) {
            const float* r = &scratch[g][b2 * 8];
            const float s01 = __fadd_rn(r[0], r[1]);
            const float s23 = __fadd_rn(r[2], r[3]);
            const float s45 = __fadd_rn(r[4], r[5]);
            const float s67 = __fadd_rn(r[6], r[7]);
            B[b2] = __fadd_rn(__fadd_rn(s01, s23), __fadd_rn(s45, s67));
        }
        const float c0 = __fadd_rn(B[0], B[1]);
        const float c1 = __fadd_rn(B[2], B[3]);
        const float c2 = __fadd_rn(B[4], B[5]);
        const float c3 = __fadd_rn(B[6], B[7]);
        partV[row] = __fadd_rn(__fadd_rn(c0, c1), __fadd_rn(c2, c3));
    }
}

// ---------------------------------------------------------------------------
// K3 (main): BN + LIF from stored y; mean/rs chains are block-uniform ->
// computed by wave 0 only and broadcast via LDS (identical add chains).
// Nontemporal out stores (out never re-read).
// ---------------------------------------------------------------------------
__global__ __launch_bounds__(256) void lif_from_y_im(
    const float* __restrict__ y, const float* __restrict__ partM,
    const float* __restrict__ partV,
    const float* __restrict__ gamma, const float* __restrict__ beta,
    float* __restrict__ out)
{
    __shared__ float sh[2];
    const int tid = threadIdx.x;
    const int o = blockIdx.x;
    const int b = blockIdx.y;
    const int m0 = tid * 4;

    if (tid < 64) {
        float Sm = 0.0f;
#pragma unroll 16
        for (int tb = 0; tb < 128; ++tb)
            Sm = __fadd_rn(Sm, partM[(size_t)tb * 256 + o]);
        float Sv = 0.0f;
#pragma unroll 16
        for (int tb = 0; tb < 128; ++tb)
            Sv = __fadd_rn(Sv, partV[(size_t)tb * 256 + o]);
        if (tid == 0) {
            const float mean = Sm * (1.0f / 131072.0f);
            const float var  = Sv * (1.0f / 131072.0f);
            const float vp   = __fadd_rn(var, 1e-5f);
            sh[0] = mean;
            sh[1] = __fdiv_rn(1.0f, __fsqrt_rn(vp));
        }
    }
    __syncthreads();
    const float mean = sh[0];
    const float rs   = sh[1];

    const float g    = gamma[o];
    const float be   = beta[o];

    float v0 = 0.0f, v1 = 0.0f, v2 = 0.0f, v3 = 0.0f;

    for (int t = 0; t < TT; ++t) {
        const size_t off = ((size_t)(t * BB + b) * CC + o) * MM + m0;
        const float4 yv = *(const float4*)(y + off);

        const float n0 = __fadd_rn(__fmul_rn(__fmul_rn(__fsub_rn(yv.x, mean), rs), g), be);
        const float n1 = __fadd_rn(__fmul_rn(__fmul_rn(__fsub_rn(yv.y, mean), rs), g), be);
        const float n2 = __fadd_rn(__fmul_rn(__fmul_rn(__fsub_rn(yv.z, mean), rs), g), be);
        const float n3 = __fadd_rn(__fmul_rn(__fmul_rn(__fsub_rn(yv.w, mean), rs), g), be);

        v0 = __fadd_rn(v0, __fmul_rn(__fsub_rn(n0, v0), 0.5f));
        v1 = __fadd_rn(v1, __fmul_rn(__fsub_rn(n1, v1), 0.5f));
        v2 = __fadd_rn(v2, __fmul_rn(__fsub_rn(n2, v2), 0.5f));
        v3 = __fadd_rn(v3, __fmul_rn(__fsub_rn(n3, v3), 0.5f));

        const bool s0 = (v0 >= 1.0f);
        const bool s1 = (v1 >= 1.0f);
        const bool s2 = (v2 >= 1.0f);
        const bool s3 = (v3 >= 1.0f);
        if (s0) v0 = 0.0f;
        if (s1) v1 = 0.0f;
        if (s2) v2 = 0.0f;
        if (s3) v3 = 0.0f;

        fx4 sv;
        sv.x = s0 ? 1.0f : 0.0f; sv.y = s1 ? 1.0f : 0.0f;
        sv.z = s2 ? 1.0f : 0.0f; sv.w = s3 ? 1.0f : 0.0f;
        __builtin_nontemporal_store(sv, (fx4*)(out + off));
    }
}

// ---------------------------------------------------------------------------
// Mid path (R10 graph) kernels, kept for the unlikely case ws fits old need
// but not new need.
// ---------------------------------------------------------------------------
__global__ void reduce_mean(const float* __restrict__ part,
                            float* __restrict__ mv)
{
    const int o = threadIdx.x;
    float S = 0.0f;
    for (int tb = 0; tb < 128; ++tb)
        S = __fadd_rn(S, part[(size_t)tb * 256 + o]);
    mv[o] = S * (1.0f / 131072.0f);   // /2^17 exact
}

__global__ __launch_bounds__(256) void var_partial_y(
    const float* __restrict__ y, const float* __restrict__ mv,
    float* __restrict__ part)
{
    __shared__ float yrow[4][1024];
    __shared__ float scratch[4][64];
    const int tid  = threadIdx.x;
    const int g    = tid >> 6;
    const int lane = tid & 63;
    const size_t row = (size_t)blockIdx.x * 4 + g;
    const float* yr = y + row * MM;
    const float mean = mv[row & 255];

#pragma unroll
    for (int q = 0; q < 4; ++q) {
        const float4 yv = *(const float4*)(yr + q * 256 + lane * 4);
        const float d0 = __fsub_rn(yv.x, mean);
        const float d1 = __fsub_rn(yv.y, mean);
        const float d2 = __fsub_rn(yv.z, mean);
        const float d3 = __fsub_rn(yv.w, mean);
        *(float4*)&yrow[g][q * 256 + lane * 4] =
            make_float4(__fmul_rn(d0, d0), __fmul_rn(d1, d1),
                        __fmul_rn(d2, d2), __fmul_rn(d3, d3));
    }
    __syncthreads();

    {
        const int blk = lane >> 3;
        const int k   = lane & 7;
        const float* p = &yrow[g][blk * 128 + k];
        float r = p[0];
#pragma unroll
        for (int i = 1; i < 16; ++i) r = __fadd_rn(r, p[8 * i]);
        scratch[g][lane] = r;
    }
    __syncthreads();

    if (lane == 0) {
        float B[8];
#pragma unroll
        for (int b2 = 0; b2 < 8; ++b2) {
            const float* r = &scratch[g][b2 * 8];
            const float s01 = __fadd_rn(r[0], r[1]);
            const float s23 = __fadd_rn(r[2], r[3]);
            const float s45 = __fadd_rn(r[4], r[5]);
            const float s67 = __fadd_rn(r[6], r[7]);
            B[b2] = __fadd_rn(__fadd_rn(s01, s23), __fadd_rn(s45, s67));
        }
        const float c0 = __fadd_rn(B[0], B[1]);
        const float c1 = __fadd_rn(B[2], B[3]);
        const float c2 = __fadd_rn(B[4], B[5]);
        const float c3 = __fadd_rn(B[6], B[7]);
        part[row] = __fadd_rn(__fadd_rn(c0, c1), __fadd_rn(c2, c3));
    }
}

__global__ __launch_bounds__(256) void lif_from_y(
    const float* __restrict__ y, const float* __restrict__ mv,
    const float* __restrict__ part,
    const float* __restrict__ gamma, const float* __restrict__ beta,
    float* __restrict__ out)
{
    const int tid = threadIdx.x;
    const int o = blockIdx.x;
    const int b = blockIdx.y;
    const int m0 = tid * 4;

    const float mean = mv[o];

    float S = 0.0f;
#pragma unroll 16
    for (int tb = 0; tb < 128; ++tb)
        S = __fadd_rn(S, part[(size_t)tb * 256 + o]);
    const float var = S * (1.0f / 131072.0f);
    const float vp  = __fadd_rn(var, 1e-5f);
    const float rs  = __fdiv_rn(1.0f, __fsqrt_rn(vp));

    const float g    = gamma[o];
    const float be   = beta[o];

    float v0 = 0.0f, v1 = 0.0f, v2 = 0.0f, v3 = 0.0f;

    for (int t = 0; t < TT; ++t) {
        const size_t off = ((size_t)(t * BB + b) * CC + o) * MM + m0;
        const float4 yv = *(const float4*)(y + off);

        const float n0 = __fadd_rn(__fmul_rn(__fmul_rn(__fsub_rn(yv.x, mean), rs), g), be);
        const float n1 = __fadd_rn(__fmul_rn(__fmul_rn(__fsub_rn(yv.y, mean), rs), g), be);
        const float n2 = __fadd_rn(__fmul_rn(__fmul_rn(__fsub_rn(yv.z, mean), rs), g), be);
        const float n3 = __fadd_rn(__fmul_rn(__fmul_rn(__fsub_rn(yv.w, mean), rs), g), be);

        v0 = __fadd_rn(v0, __fmul_rn(__fsub_rn(n0, v0), 0.5f));
        v1 = __fadd_rn(v1, __fmul_rn(__fsub_rn(n1, v1), 0.5f));
        v2 = __fadd_rn(v2, __fmul_rn(__fsub_rn(n2, v2), 0.5f));
        v3 = __fadd_rn(v3, __fmul_rn(__fsub_rn(n3, v3), 0.5f));

        const bool s0 = (v0 >= 1.0f);
        const bool s1 = (v1 >= 1.0f);
        const bool s2 = (v2 >= 1.0f);
        const bool s3 = (v3 >= 1.0f);
        if (s0) v0 = 0.0f;
        if (s1) v1 = 0.0f;
        if (s2) v2 = 0.0f;
        if (s3) v3 = 0.0f;

        *(float4*)(out + off) = make_float4(s0 ? 1.0f : 0.0f, s1 ? 1.0f : 0.0f,
                                            s2 ? 1.0f : 0.0f, s3 ? 1.0f : 0.0f);
    }
}

__global__ void reduce_var(const float* __restrict__ part,
                           float* __restrict__ mv)
{
    const int o = threadIdx.x;
    float S = 0.0f;
    for (int tb = 0; tb < 128; ++tb)
        S = __fadd_rn(S, part[(size_t)tb * 256 + o]);
    const float var = S * (1.0f / 131072.0f);
    const float vp  = __fadd_rn(var, 1e-5f);
    mv[256 + o] = __fdiv_rn(1.0f, __fsqrt_rn(vp));
}

// ---------------------------------------------------------------------------
// Fallback path (R5, verified): recompute einsum in each pass. Only used if
// ws cannot hold y (not expected on this harness).
// ---------------------------------------------------------------------------
__device__ __forceinline__ void e1_row4(
    const float* __restrict__ x, const float* __restrict__ W,
    int t, int b, int o, int m0,
    float& y0, float& y1, float& y2, float& y3)
{
    const float* xs = x + ((size_t)(t * BB + b) * CC) * MM + m0;
    const float* wr = W + (size_t)o * CC;
    y0 = 0.0f; y1 = 0.0f; y2 = 0.0f; y3 = 0.0f;
    for (int c = 0; c < CC; ++c) {
        const float wc = wr[c];
        const float4 xv = *(const float4*)(xs + (size_t)c * MM);
        y0 = __fadd_rn(y0, __fmul_rn(wc, xv.x));
        y1 = __fadd_rn(y1, __fmul_rn(wc, xv.y));
        y2 = __fadd_rn(y2, __fmul_rn(wc, xv.z));
        y3 = __fadd_rn(y3, __fmul_rn(wc, xv.w));
    }
}

__device__ __forceinline__ float np_pairwise_1024(
    const float* __restrict__ yrow, float* __restrict__ scratch, int tid)
{
    if (tid < 64) {
        const int blk = tid >> 3;
        const int k   = tid & 7;
        const float* p = yrow + blk * 128 + k;
        float r = p[0];
#pragma unroll
        for (int i = 1; i < 16; ++i) r = __fadd_rn(r, p[8 * i]);
        scratch[tid] = r;
    }
    __syncthreads();
    if (tid == 0) {
        float B[8];
#pragma unroll
        for (int blk = 0; blk < 8; ++blk) {
            const float* r = scratch + blk * 8;
            const float s01 = __fadd_rn(r[0], r[1]);
            const float s23 = __fadd_rn(r[2], r[3]);
            const float s45 = __fadd_rn(r[4], r[5]);
            const float s67 = __fadd_rn(r[6], r[7]);
            B[blk] = __fadd_rn(__fadd_rn(s01, s23), __fadd_rn(s45, s67));
        }
        const float c0 = __fadd_rn(B[0], B[1]);
        const float c1 = __fadd_rn(B[2], B[3]);
        const float c2 = __fadd_rn(B[4], B[5]);
        const float c3 = __fadd_rn(B[6], B[7]);
        scratch[64] = __fadd_rn(__fadd_rn(c0, c1), __fadd_rn(c2, c3));
    }
    __syncthreads();
    return scratch[64];
}

__global__ __launch_bounds__(256) void pass_mean_fb(
    const float* __restrict__ x, const float* __restrict__ W,
    float* __restrict__ part)
{
    __shared__ float yrow[1024];
    __shared__ float scratch[65];
    const int tid = threadIdx.x;
    const int o  = blockIdx.x;
    const int tb = blockIdx.y;
    const int m0 = tid * 4;
    float y0, y1, y2, y3;
    e1_row4(x, W, tb >> 4, tb & 15, o, m0, y0, y1, y2, y3);
    *(float4*)&yrow[m0] = make_float4(y0, y1, y2, y3);
    __syncthreads();
    const float P = np_pairwise_1024(yrow, scratch, tid);
    if (tid == 0) part[(size_t)tb * 256 + o] = P;
}

__global__ __launch_bounds__(256) void pass_var_fb(
    const float* __restrict__ x, const float* __restrict__ W,
    const float* __restrict__ mv, float* __restrict__ part)
{
    __shared__ float yrow[1024];
    __shared__ float scratch[65];
    const int tid = threadIdx.x;
    const int o  = blockIdx.x;
    const int tb = blockIdx.y;
    const int m0 = tid * 4;
    const float mean = mv[o];
    float y0, y1, y2, y3;
    e1_row4(x, W, tb >> 4, tb & 15, o, m0, y0, y1, y2, y3);
    const float d0 = __fsub_rn(y0, mean);
    const float d1 = __fsub_rn(y1, mean);
    const float d2 = __fsub_rn(y2, mean);
    const float d3 = __fsub_rn(y3, mean);
    *(float4*)&yrow[m0] = make_float4(__fmul_rn(d0, d0), __fmul_rn(d1, d1),
                                      __fmul_rn(d2, d2), __fmul_rn(d3, d3));
    __syncthreads();
    const float P = np_pairwise_1024(yrow, scratch, tid);
    if (tid == 0) part[(size_t)tb * 256 + o] = P;
}

__global__ __launch_bounds__(256) void pass_lif_fb(
    const float* __restrict__ x, const float* __restrict__ W,
    const float* __restrict__ mv,
    const float* __restrict__ gamma, const float* __restrict__ beta,
    float* __restrict__ out)
{
    const int tid = threadIdx.x;
    const int o = blockIdx.x;
    const int b = blockIdx.y;
    const int m0 = tid * 4;
    const float mean = mv[o];
    const float rs   = mv[256 + o];
    const float g    = gamma[o];
    const float be   = beta[o];
    float v0 = 0.0f, v1 = 0.0f, v2 = 0.0f, v3 = 0.0f;
    for (int t = 0; t < TT; ++t) {
        float y0, y1, y2, y3;
        e1_row4(x, W, t, b, o, m0, y0, y1, y2, y3);
        const float n0 = __fadd_rn(__fmul_rn(__fmul_rn(__fsub_rn(y0, mean), rs), g), be);
        const float n1 = __fadd_rn(__fmul_rn(__fmul_rn(__fsub_rn(y1, mean), rs), g), be);
        const float n2 = __fadd_rn(__fmul_rn(__fmul_rn(__fsub_rn(y2, mean), rs), g), be);
        const float n3 = __fadd_rn(__fmul_rn(__fmul_rn(__fsub_rn(y3, mean), rs), g), be);
        v0 = __fadd_rn(v0, __fmul_rn(__fsub_rn(n0, v0), 0.5f));
        v1 = __fadd_rn(v1, __fmul_rn(__fsub_rn(n1, v1), 0.5f));
        v2 = __fadd_rn(v2, __fmul_rn(__fsub_rn(n2, v2), 0.5f));
        v3 = __fadd_rn(v3, __fmul_rn(__fsub_rn(n3, v3), 0.5f));
        const bool s0 = (v0 >= 1.0f);
        const bool s1 = (v1 >= 1.0f);
        const bool s2 = (v2 >= 1.0f);
        const bool s3 = (v3 >= 1.0f);
        if (s0) v0 = 0.0f;
        if (s1) v1 = 0.0f;
        if (s2) v2 = 0.0f;
        if (s3) v3 = 0.0f;
        const size_t off = ((size_t)(t * BB + b) * CC + o) * MM + m0;
        *(float4*)(out + off) = make_float4(s0 ? 1.0f : 0.0f, s1 ? 1.0f : 0.0f,
                                            s2 ? 1.0f : 0.0f, s3 ? 1.0f : 0.0f);
    }
}

// ---------------------------------------------------------------------------
extern "C" void kernel_launch(void* const* d_in, const int* in_sizes, int n_in,
                              void* d_out, int out_size, void* d_ws, size_t ws_size,
                              hipStream_t stream)
{
    const float* x     = (const float*)d_in[0];
    const float* W     = (const float*)d_in[1];
    const float* gamma = (const float*)d_in[2];
    const float* beta  = (const float*)d_in[3];
    float* out = (float*)d_out;

    const size_t need_new = ((size_t)NY + 2 * 128 * 256) * sizeof(float);
    const size_t need_old = ((size_t)NY + 128 * 256 + 512) * sizeof(float);

    if (ws_size >= need_new) {
        float* y     = (float*)d_ws;
        float* partM = y + NY;
        float* partV = partM + 128 * 256;

        einsum_store_mean<<<dim3(2048), dim3(256), 0, stream>>>(x, W, y, partM);
        var_partial_im<<<dim3(8192), dim3(256), 0, stream>>>(y, partM, partV);
        lif_from_y_im<<<dim3(256, 16), dim3(256), 0, stream>>>(y, partM, partV,
                                                               gamma, beta, out);
    } else if (ws_size >= need_old) {
        float* y    = (float*)d_ws;
        float* part = y + NY;
        float* mv   = part + 128 * 256;

        einsum_store_mean<<<dim3(2048), dim3(256), 0, stream>>>(x, W, y, part);
        reduce_mean<<<dim3(1), dim3(256), 0, stream>>>(part, mv);
        var_partial_y<<<dim3(8192), dim3(256), 0, stream>>>(y, mv, part);
        lif_from_y<<<dim3(256, 16), dim3(256), 0, stream>>>(y, mv, part, gamma, beta, out);
    } else {
        float* part = (float*)d_ws;
        float* mv   = part + 128 * 256;
        pass_mean_fb<<<dim3(256, 128), dim3(256), 0, stream>>>(x, W, part);
        reduce_mean<<<dim3(1), dim3(256), 0, stream>>>(part, mv);
        pass_var_fb<<<dim3(256, 128), dim3(256), 0, stream>>>(x, W, mv, part);
        reduce_var<<<dim3(1), dim3(256), 0, stream>>>(part, mv);
        pass_lif_fb<<<dim3(256, 16), dim3(256), 0, stream>>>(x, W, mv, gamma, beta, out);
    }
}